// Round 1
// baseline (1226.364 us; speedup 1.0000x reference)
//
#include <hip/hip_runtime.h>
#include <hip/hip_bf16.h>

// Problem: out[m,n] = sum_r sum_k inp[r,m,k] * wgt[r,n,k]
// W=8, M=N=4096, K=1792  -> single GEMM M=4096, N=4096, Ktot=14336
// Inputs fp32; cast to bf16 (error budget ~3e-3 << 3.4e-2 threshold), MFMA accumulate fp32.

#define Wsz 8
#define Mdim 4096
#define Ndim 4096
#define Kshard 1792
#define KTOT 14336   // Wsz * Kshard

typedef __attribute__((ext_vector_type(8))) short short8;
typedef __attribute__((ext_vector_type(4))) float f32x4;

__device__ __forceinline__ unsigned short f2bf(float x) {
    unsigned u = __builtin_bit_cast(unsigned, x);
    u = (u + 0x7FFFu + ((u >> 16) & 1u)) >> 16;   // RNE
    return (unsigned short)u;
}

// ---------------------------------------------------------------------------
// Convert + reshuffle: src [W][4096][1792] f32  ->  dst [4096][W*1792] bf16
// One float4 per thread. total groups = 8*4096*448 = 14,680,064
// ---------------------------------------------------------------------------
__global__ void cvt_kernel(const float* __restrict__ src, unsigned short* __restrict__ dst) {
    unsigned g = blockIdx.x * blockDim.x + threadIdx.x;   // < 14,680,064
    unsigned k4 = g % 448u;            // float4 index within the 1792-row
    unsigned t  = g / 448u;
    unsigned m  = t & 4095u;
    unsigned r  = t >> 12;
    const float4 v = *(const float4*)(src + ((long)r * Mdim * Kshard + (long)m * Kshard + k4 * 4));
    ushort4 o;
    o.x = f2bf(v.x); o.y = f2bf(v.y); o.z = f2bf(v.z); o.w = f2bf(v.w);
    *(ushort4*)(dst + ((long)m * KTOT + (long)r * Kshard + k4 * 4)) = o;
}

// ---------------------------------------------------------------------------
// m97-structure GEMM: C[4096,4096] = A[4096,KTOT] * B[4096,KTOT]^T (bf16, f32 acc)
// 128x128 tile, BK=32, 4 waves, each wave 64x64 = 4x4 mfma_f32_16x16x32_bf16
// global_load_lds width=16 staging, ds_read_b128 fragment loads.
// ---------------------------------------------------------------------------
__global__ void __launch_bounds__(256) gemm_bt(const unsigned short* __restrict__ A,
                                               const unsigned short* __restrict__ B,
                                               float* __restrict__ C) {
    __shared__ short As[128 * 32];   // 8 KiB, row-major [row][32]
    __shared__ short Bs[128 * 32];

    const int tid = threadIdx.x;
    const int w = tid >> 6, lane = tid & 63;
    const int bm = blockIdx.y * 128, bn = blockIdx.x * 128;
    const int wm = (w >> 1) * 64, wn = (w & 1) * 64;
    const int lane15 = lane & 15, quad = lane >> 4;

    // staging: round0 rows w*16 + lane/4, round1 = +64 rows; 16B chunk = (lane&3)*8 bf16
    const unsigned short* a0 = A + (size_t)(bm + w * 16 + (lane >> 2)) * KTOT + (lane & 3) * 8;
    const unsigned short* b0 = B + (size_t)(bn + w * 16 + (lane >> 2)) * KTOT + (lane & 3) * 8;
    char* ldsA = (char*)As + w * 1024;   // wave-uniform base; HW writes base + lane*16
    char* ldsB = (char*)Bs + w * 1024;

    const char* a_rd = (const char*)As + ((size_t)(wm + lane15) * 32 + quad * 8) * 2;
    const char* b_rd = (const char*)Bs + ((size_t)(wn + lane15) * 32 + quad * 8) * 2;

    f32x4 acc[4][4] = {};

    for (int kt = 0; kt < KTOT; kt += 32) {
        __syncthreads();   // previous compute done before overwriting LDS
        __builtin_amdgcn_global_load_lds((const __attribute__((address_space(1))) void*)a0,
                                         (__attribute__((address_space(3))) void*)ldsA, 16, 0, 0);
        __builtin_amdgcn_global_load_lds((const __attribute__((address_space(1))) void*)(a0 + 64 * (size_t)KTOT),
                                         (__attribute__((address_space(3))) void*)(ldsA + 4096), 16, 0, 0);
        __builtin_amdgcn_global_load_lds((const __attribute__((address_space(1))) void*)b0,
                                         (__attribute__((address_space(3))) void*)ldsB, 16, 0, 0);
        __builtin_amdgcn_global_load_lds((const __attribute__((address_space(1))) void*)(b0 + 64 * (size_t)KTOT),
                                         (__attribute__((address_space(3))) void*)(ldsB + 4096), 16, 0, 0);
        a0 += 32; b0 += 32;
        __syncthreads();   // compiler emits vmcnt(0) drain before s_barrier

        short8 af[4], bfr[4];
#pragma unroll
        for (int i = 0; i < 4; ++i) {
            af[i]  = *(const short8*)(a_rd + (size_t)i * 16 * 64);   // 16 rows * 64B/row
            bfr[i] = *(const short8*)(b_rd + (size_t)i * 16 * 64);
        }
#pragma unroll
        for (int mi = 0; mi < 4; ++mi)
#pragma unroll
            for (int ni = 0; ni < 4; ++ni)
                acc[mi][ni] = __builtin_amdgcn_mfma_f32_16x16x32_bf16(af[mi], bfr[ni], acc[mi][ni], 0, 0, 0);
    }

    // C/D layout (measured m89/m91): col = lane&15, row = quad*4 + reg
#pragma unroll
    for (int mi = 0; mi < 4; ++mi)
#pragma unroll
        for (int ni = 0; ni < 4; ++ni) {
            const int col = bn + wn + ni * 16 + lane15;
#pragma unroll
            for (int r2 = 0; r2 < 4; ++r2) {
                const int row = bm + wm + mi * 16 + quad * 4 + r2;
                C[(size_t)row * Ndim + col] = acc[mi][ni][r2];
            }
        }
}

// ---------------------------------------------------------------------------
// Fallback (ws too small): same tile structure, inline fp32->bf16 VGPR staging.
// A/B read directly from [W][4096][1792] fp32; BK=32 divides Kshard so each
// K-tile lies inside one rank shard.
// ---------------------------------------------------------------------------
__global__ void __launch_bounds__(256) gemm_inline(const float* __restrict__ A,
                                                   const float* __restrict__ B,
                                                   float* __restrict__ C) {
    __shared__ short As[128 * 32];
    __shared__ short Bs[128 * 32];

    const int tid = threadIdx.x;
    const int w = tid >> 6, lane = tid & 63;
    const int bm = blockIdx.y * 128, bn = blockIdx.x * 128;
    const int wm = (w >> 1) * 64, wn = (w & 1) * 64;
    const int lane15 = lane & 15, quad = lane >> 4;

    const int srow = tid >> 3;        // 0..31 (round adds 32)
    const int skc  = (tid & 7) * 4;   // float offset within 32-wide K tile

    const char* a_rd = (const char*)As + ((size_t)(wm + lane15) * 32 + quad * 8) * 2;
    const char* b_rd = (const char*)Bs + ((size_t)(wn + lane15) * 32 + quad * 8) * 2;

    f32x4 acc[4][4] = {};
    long base = 0; int kloc = 0;

    for (int kt = 0; kt < KTOT; kt += 32) {
        const float* ap = A + base + kloc + (long)(bm + srow) * Kshard + skc;
        const float* bp = B + base + kloc + (long)(bn + srow) * Kshard + skc;
        float4 av[4], bv[4];
#pragma unroll
        for (int i = 0; i < 4; ++i) {
            av[i] = *(const float4*)(ap + (long)i * 32 * Kshard);
            bv[i] = *(const float4*)(bp + (long)i * 32 * Kshard);
        }
        __syncthreads();
#pragma unroll
        for (int i = 0; i < 4; ++i) {
            ushort4 oa, ob;
            oa.x = f2bf(av[i].x); oa.y = f2bf(av[i].y); oa.z = f2bf(av[i].z); oa.w = f2bf(av[i].w);
            ob.x = f2bf(bv[i].x); ob.y = f2bf(bv[i].y); ob.z = f2bf(bv[i].z); ob.w = f2bf(bv[i].w);
            *(ushort4*)((char*)As + ((size_t)(srow + i * 32) * 32 + skc) * 2) = oa;
            *(ushort4*)((char*)Bs + ((size_t)(srow + i * 32) * 32 + skc) * 2) = ob;
        }
        __syncthreads();

        short8 af[4], bfr[4];
#pragma unroll
        for (int i = 0; i < 4; ++i) {
            af[i]  = *(const short8*)(a_rd + (size_t)i * 16 * 64);
            bfr[i] = *(const short8*)(b_rd + (size_t)i * 16 * 64);
        }
#pragma unroll
        for (int mi = 0; mi < 4; ++mi)
#pragma unroll
            for (int ni = 0; ni < 4; ++ni)
                acc[mi][ni] = __builtin_amdgcn_mfma_f32_16x16x32_bf16(af[mi], bfr[ni], acc[mi][ni], 0, 0, 0);

        kloc += 32;
        if (kloc == Kshard) { kloc = 0; base += (long)Mdim * Kshard; }
    }

#pragma unroll
    for (int mi = 0; mi < 4; ++mi)
#pragma unroll
        for (int ni = 0; ni < 4; ++ni) {
            const int col = bn + wn + ni * 16 + lane15;
#pragma unroll
            for (int r2 = 0; r2 < 4; ++r2) {
                const int row = bm + wm + mi * 16 + quad * 4 + r2;
                C[(size_t)row * Ndim + col] = acc[mi][ni][r2];
            }
        }
}

extern "C" void kernel_launch(void* const* d_in, const int* in_sizes, int n_in,
                              void* d_out, int out_size, void* d_ws, size_t ws_size,
                              hipStream_t stream) {
    const float* inp = (const float*)d_in[0];   // [8][4096][1792] f32
    const float* wgt = (const float*)d_in[1];   // [8][4096][1792] f32
    float* out = (float*)d_out;                 // [4096][4096] f32

    const size_t one_mat = (size_t)Mdim * KTOT * 2;   // 117,440,512 B
    if (ws_size >= 2 * one_mat) {
        unsigned short* Abf = (unsigned short*)d_ws;
        unsigned short* Bbf = (unsigned short*)((char*)d_ws + one_mat);
        const int cvt_blocks = (Wsz * Mdim * (Kshard / 4)) / 256;   // 57344
        cvt_kernel<<<cvt_blocks, 256, 0, stream>>>(inp, Abf);
        cvt_kernel<<<cvt_blocks, 256, 0, stream>>>(wgt, Bbf);
        dim3 grid(Ndim / 128, Mdim / 128);
        gemm_bt<<<grid, 256, 0, stream>>>(Abf, Bbf, out);
    } else {
        dim3 grid(Ndim / 128, Mdim / 128);
        gemm_inline<<<grid, 256, 0, stream>>>(inp, wgt, out);
    }
}

// Round 2
// 869.425 us; speedup vs baseline: 1.4105x; 1.4105x over previous
//
#include <hip/hip_runtime.h>
#include <hip/hip_bf16.h>

// out[m,n] = sum_r sum_k inp[r,m,k] * wgt[r,n,k]
// W=8, M=N=4096, K=1792 -> single GEMM M=N=4096, Ktot=14336, fp32 in/out,
// bf16 MFMA (absmax 7.8e-3 vs 3.39e-2 threshold in R1).

#define Wsz 8
#define Mdim 4096
#define Ndim 4096
#define Kshard 1792
#define KTOT 14336
#define LDSBUF 32768   // one pipeline stage: A 16KB + B 16KB

typedef __attribute__((ext_vector_type(8))) short short8;
typedef __attribute__((ext_vector_type(4))) float f32x4;

__device__ __forceinline__ unsigned short f2bf(float x) {
    unsigned u = __builtin_bit_cast(unsigned, x);
    u = (u + 0x7FFFu + ((u >> 16) & 1u)) >> 16;   // RNE
    return (unsigned short)u;
}

// ---------------------------------------------------------------------------
// Convert+reshuffle: src [8][4096][1792] f32 -> dst [4096][14336] bf16.
// 8 floats/thread: 2x float4 read (32B), 1x uint4 store (16B).
// ---------------------------------------------------------------------------
__global__ void __launch_bounds__(256) cvt_kernel(const float* __restrict__ src,
                                                  unsigned short* __restrict__ dst) {
    unsigned g = blockIdx.x * 256 + threadIdx.x;   // < 7,340,032
    unsigned k8 = g % 224u;
    unsigned t  = g / 224u;
    unsigned m  = t & 4095u;
    unsigned r  = t >> 12;
    const float4* p = (const float4*)(src + ((size_t)r * Mdim * Kshard + (size_t)m * Kshard + k8 * 8));
    float4 v0 = p[0], v1 = p[1];
    uint4 o;
    o.x = (unsigned)f2bf(v0.x) | ((unsigned)f2bf(v0.y) << 16);
    o.y = (unsigned)f2bf(v0.z) | ((unsigned)f2bf(v0.w) << 16);
    o.z = (unsigned)f2bf(v1.x) | ((unsigned)f2bf(v1.y) << 16);
    o.w = (unsigned)f2bf(v1.z) | ((unsigned)f2bf(v1.w) << 16);
    *(uint4*)(dst + ((size_t)m * KTOT + (size_t)r * Kshard + k8 * 8)) = o;
}

// ---------------------------------------------------------------------------
// 256x256 tile GEMM, BK=32, 512 threads (8 waves as 4Mx2N, wave = 64x128).
// Depth-2 pipeline over 4 LDS buffers; raw s_waitcnt vmcnt(4)+s_barrier so
// prefetch loads stay in flight across the barrier (hipBLASLt-style K-loop).
// LDS 16B-chunk XOR swizzle (col ^= (row>>1)&3) applied on the GLOBAL address
// side (global_load_lds LDS side must stay linear: base + lane*16).
// ---------------------------------------------------------------------------
__global__ void __launch_bounds__(512, 2) gemm_bt(const unsigned short* __restrict__ A,
                                                  const unsigned short* __restrict__ B,
                                                  float* __restrict__ C) {
    extern __shared__ char smem[];   // 4 * LDSBUF = 128 KiB

    const int tid = threadIdx.x;
    const int w = tid >> 6, lane = tid & 63;
    const int l15 = lane & 15, quad = lane >> 4;
    const int wm = (w >> 1) * 64;    // wave M offset (0..192)
    const int wn = (w & 1) * 128;    // wave N offset (0/128)
    const long bm = (long)blockIdx.y * 256, bn = (long)blockIdx.x * 256;

    // --- staging decode: 512 lanes cover 512 of 1024 16B chunks per matrix;
    // each thread issues chunk g and g+512 (rows sr and sr+128).
    // LDS chunk g sits at byte g*16 (linear). Global k-chunk for (row r, col c)
    // is q = c ^ ((r>>1)&3)  -> 2-way-max bank aliasing on fragment reads.
    const int chunk = w * 64 + lane;          // 0..511
    const int sr = chunk >> 2;                // 0..127
    const int sq = (chunk & 3) ^ ((sr >> 1) & 3);
    const unsigned short* aP0 = A + (size_t)(bm + sr) * KTOT + sq * 8;
    const unsigned short* aP1 = aP0 + (size_t)128 * KTOT;
    const unsigned short* bP0 = B + (size_t)(bn + sr) * KTOT + sq * 8;
    const unsigned short* bP1 = bP0 + (size_t)128 * KTOT;
    const int ldsW = w * 1024;                // wave-uniform LDS base offset

    // --- fragment read offsets (row stride 64B, swizzled 16B column)
    const int swz = (quad ^ ((l15 >> 1) & 3)) * 16;   // wm%8==0, wn%8==0 -> row swizzle = f(l15)
    const int aoff = (wm + l15) * 64 + swz;
    const int boff = 16384 + (wn + l15) * 64 + swz;

    f32x4 acc[4][8] = {};

#define STAGE(bufbase, kt)                                                                              \
    do {                                                                                                \
        __builtin_amdgcn_global_load_lds((const __attribute__((address_space(1))) void*)(aP0 + (kt)),   \
            (__attribute__((address_space(3))) void*)(smem + (bufbase) + ldsW), 16, 0, 0);              \
        __builtin_amdgcn_global_load_lds((const __attribute__((address_space(1))) void*)(aP1 + (kt)),   \
            (__attribute__((address_space(3))) void*)(smem + (bufbase) + ldsW + 8192), 16, 0, 0);       \
        __builtin_amdgcn_global_load_lds((const __attribute__((address_space(1))) void*)(bP0 + (kt)),   \
            (__attribute__((address_space(3))) void*)(smem + (bufbase) + 16384 + ldsW), 16, 0, 0);      \
        __builtin_amdgcn_global_load_lds((const __attribute__((address_space(1))) void*)(bP1 + (kt)),   \
            (__attribute__((address_space(3))) void*)(smem + (bufbase) + 16384 + ldsW + 8192), 16, 0, 0);\
    } while (0)

#define COMPUTE(bufbase)                                                                 \
    do {                                                                                 \
        short8 af[4], bfr[8];                                                            \
        _Pragma("unroll") for (int i = 0; i < 4; ++i)                                    \
            af[i] = *(const short8*)(smem + (bufbase) + aoff + i * 1024);                \
        _Pragma("unroll") for (int i = 0; i < 8; ++i)                                    \
            bfr[i] = *(const short8*)(smem + (bufbase) + boff + i * 1024);               \
        _Pragma("unroll") for (int mi = 0; mi < 4; ++mi)                                 \
            _Pragma("unroll") for (int ni = 0; ni < 8; ++ni)                             \
                acc[mi][ni] = __builtin_amdgcn_mfma_f32_16x16x32_bf16(af[mi], bfr[ni],   \
                                                                      acc[mi][ni], 0, 0, 0); \
    } while (0)

#define PIPE_BAR4() asm volatile("s_waitcnt vmcnt(4)\ns_barrier" ::: "memory")
#define PIPE_BAR0() asm volatile("s_waitcnt vmcnt(0)\ns_barrier" ::: "memory")

    STAGE(0, 0);          // iter 0 -> buf 0
    STAGE(LDSBUF, 32);    // iter 1 -> buf 1

    long kt = 0;
    // 448 iterations total; main loop covers 0..443 (111 x 4-unroll, static buf ids)
    for (int blk = 0; blk < 111; ++blk) {
#pragma unroll
        for (int u = 0; u < 4; ++u) {
            PIPE_BAR4();                          // oldest 4 loads (this buf) done; newer 4 stay in flight
            STAGE(((u + 2) & 3) * LDSBUF, kt + 64);
            COMPUTE(u * LDSBUF);
            kt += 32;
        }
    }
    // tail: iters 444..447 (kt = 14208)
    PIPE_BAR4(); STAGE(2 * LDSBUF, kt + 64); COMPUTE(0);          kt += 32;  // 444
    PIPE_BAR4(); STAGE(3 * LDSBUF, kt + 64); COMPUTE(LDSBUF);     kt += 32;  // 445
    PIPE_BAR4();                             COMPUTE(2 * LDSBUF);            // 446
    PIPE_BAR0();                             COMPUTE(3 * LDSBUF);            // 447

#undef STAGE
#undef COMPUTE
#undef PIPE_BAR4
#undef PIPE_BAR0

    // C/D layout (m89/m91): col = lane&15, row = quad*4 + reg
#pragma unroll
    for (int mi = 0; mi < 4; ++mi)
#pragma unroll
        for (int ni = 0; ni < 8; ++ni) {
            const long col = bn + wn + ni * 16 + l15;
#pragma unroll
            for (int r2 = 0; r2 < 4; ++r2) {
                const long row = bm + wm + mi * 16 + quad * 4 + r2;
                C[row * Ndim + col] = acc[mi][ni][r2];
            }
        }
}

// ---------------------------------------------------------------------------
// Fallback (ws too small): R1's inline-convert 128x128 kernel, unchanged.
// ---------------------------------------------------------------------------
__global__ void __launch_bounds__(256) gemm_inline(const float* __restrict__ A,
                                                   const float* __restrict__ B,
                                                   float* __restrict__ C) {
    __shared__ short As[128 * 32];
    __shared__ short Bs[128 * 32];

    const int tid = threadIdx.x;
    const int w = tid >> 6, lane = tid & 63;
    const int bm = blockIdx.y * 128, bn = blockIdx.x * 128;
    const int wm = (w >> 1) * 64, wn = (w & 1) * 64;
    const int lane15 = lane & 15, quad = lane >> 4;

    const int srow = tid >> 3;
    const int skc  = (tid & 7) * 4;

    const char* a_rd = (const char*)As + ((size_t)(wm + lane15) * 32 + quad * 8) * 2;
    const char* b_rd = (const char*)Bs + ((size_t)(wn + lane15) * 32 + quad * 8) * 2;

    f32x4 acc[4][4] = {};
    long base = 0; int kloc = 0;

    for (int kt = 0; kt < KTOT; kt += 32) {
        const float* ap = A + base + kloc + (long)(bm + srow) * Kshard + skc;
        const float* bp = B + base + kloc + (long)(bn + srow) * Kshard + skc;
        float4 av[4], bv[4];
#pragma unroll
        for (int i = 0; i < 4; ++i) {
            av[i] = *(const float4*)(ap + (long)i * 32 * Kshard);
            bv[i] = *(const float4*)(bp + (long)i * 32 * Kshard);
        }
        __syncthreads();
#pragma unroll
        for (int i = 0; i < 4; ++i) {
            ushort4 oa, ob;
            oa.x = f2bf(av[i].x); oa.y = f2bf(av[i].y); oa.z = f2bf(av[i].z); oa.w = f2bf(av[i].w);
            ob.x = f2bf(bv[i].x); ob.y = f2bf(bv[i].y); ob.z = f2bf(bv[i].z); ob.w = f2bf(bv[i].w);
            *(ushort4*)((char*)As + ((size_t)(srow + i * 32) * 32 + skc) * 2) = oa;
            *(ushort4*)((char*)Bs + ((size_t)(srow + i * 32) * 32 + skc) * 2) = ob;
        }
        __syncthreads();

        short8 af[4], bfr[4];
#pragma unroll
        for (int i = 0; i < 4; ++i) {
            af[i]  = *(const short8*)(a_rd + (size_t)i * 16 * 64);
            bfr[i] = *(const short8*)(b_rd + (size_t)i * 16 * 64);
        }
#pragma unroll
        for (int mi = 0; mi < 4; ++mi)
#pragma unroll
            for (int ni = 0; ni < 4; ++ni)
                acc[mi][ni] = __builtin_amdgcn_mfma_f32_16x16x32_bf16(af[mi], bfr[ni], acc[mi][ni], 0, 0, 0);

        kloc += 32;
        if (kloc == Kshard) { kloc = 0; base += (long)Mdim * Kshard; }
    }

#pragma unroll
    for (int mi = 0; mi < 4; ++mi)
#pragma unroll
        for (int ni = 0; ni < 4; ++ni) {
            const int col = bn + wn + ni * 16 + lane15;
#pragma unroll
            for (int r2 = 0; r2 < 4; ++r2) {
                const int row = bm + wm + mi * 16 + quad * 4 + r2;
                C[(size_t)row * Ndim + col] = acc[mi][ni][r2];
            }
        }
}

extern "C" void kernel_launch(void* const* d_in, const int* in_sizes, int n_in,
                              void* d_out, int out_size, void* d_ws, size_t ws_size,
                              hipStream_t stream) {
    const float* inp = (const float*)d_in[0];   // [8][4096][1792] f32
    const float* wgt = (const float*)d_in[1];   // [8][4096][1792] f32
    float* out = (float*)d_out;                 // [4096][4096] f32

    const size_t one_mat = (size_t)Mdim * KTOT * 2;   // 117,440,512 B
    if (ws_size >= 2 * one_mat) {
        unsigned short* Abf = (unsigned short*)d_ws;
        unsigned short* Bbf = (unsigned short*)((char*)d_ws + one_mat);
        const int cvt_blocks = (Wsz * Mdim * (Kshard / 8)) / 256;   // 28672
        cvt_kernel<<<cvt_blocks, 256, 0, stream>>>(inp, Abf);
        cvt_kernel<<<cvt_blocks, 256, 0, stream>>>(wgt, Bbf);
        hipFuncSetAttribute(reinterpret_cast<const void*>(gemm_bt),
                            hipFuncAttributeMaxDynamicSharedMemorySize, 4 * LDSBUF);
        dim3 grid(Ndim / 256, Mdim / 256);
        gemm_bt<<<grid, 512, 4 * LDSBUF, stream>>>(Abf, Bbf, out);
    } else {
        dim3 grid(Ndim / 128, Mdim / 128);
        gemm_inline<<<grid, 256, 0, stream>>>(inp, wgt, out);
    }
}